// Round 1
// baseline (1773.359 us; speedup 1.0000x reference)
//
#include <hip/hip_runtime.h>

typedef __attribute__((ext_vector_type(4))) float f32x4;
typedef __attribute__((ext_vector_type(8))) short short8;

#define T_LEN 2048
#define B_SZ 256
#define FEATN 128
#define H 50
#define H3 150
#define XW_STRIDE 160

__device__ __forceinline__ unsigned short f2bf(float f) {
  unsigned int u = __float_as_uint(f);
  u = (u + 0x7fffu + ((u >> 16) & 1u)) >> 16;
  return (unsigned short)u;
}
__device__ __forceinline__ float bf2f(unsigned short s) {
  return __uint_as_float(((unsigned int)s) << 16);
}

// ---------------- Phase 1: xw[m][k] = x[m][:] @ W[:][k]  (bf16 out, no bias) ----
// m = b*T + t.  Grid: 4096 blocks x 256 threads; each block does 128 rows
// (4 waves x 2 M-tiles of 16).  W^T staged in LDS as bf16 (rows = n, contiguous k).
__global__ __launch_bounds__(256) void xw_gemm(const float* __restrict__ x,
                                               const float* __restrict__ W,
                                               unsigned short* __restrict__ xw) {
  __shared__ unsigned short Wt[160 * 136];  // [n][k], row stride 136 (16B-aligned rows)
  const int tid = threadIdx.x;
  for (int idx = tid; idx < FEATN * H3; idx += 256) {
    int f = idx / H3;
    int n = idx - f * H3;
    Wt[n * 136 + f] = f2bf(W[idx]);
  }
  for (int idx = tid; idx < 10 * FEATN; idx += 256) {  // zero-pad n = 150..159
    int n = H3 + (idx >> 7);
    int f = idx & 127;
    Wt[n * 136 + f] = 0;
  }
  __syncthreads();

  const int wid = tid >> 6;
  const int lane = tid & 63;
  const int l15 = lane & 15;
  const int g = lane >> 4;
  const long row0 = (long)blockIdx.x * 128 + wid * 32;

  // A fragments: 2 M-tiles x 4 k-steps, each lane: row = l15, k = kk*32 + g*8 + j
  short8 a[2][4];
#pragma unroll
  for (int sub = 0; sub < 2; ++sub) {
    const float* xp = x + (row0 + sub * 16 + l15) * FEATN + g * 8;
#pragma unroll
    for (int kk = 0; kk < 4; ++kk) {
      f32x4 p0 = *(const f32x4*)(xp + kk * 32);
      f32x4 p1 = *(const f32x4*)(xp + kk * 32 + 4);
      short8 v;
      v[0] = (short)f2bf(p0[0]); v[1] = (short)f2bf(p0[1]);
      v[2] = (short)f2bf(p0[2]); v[3] = (short)f2bf(p0[3]);
      v[4] = (short)f2bf(p1[0]); v[5] = (short)f2bf(p1[1]);
      v[6] = (short)f2bf(p1[2]); v[7] = (short)f2bf(p1[3]);
      a[sub][kk] = v;
    }
  }

  for (int nt = 0; nt < 10; ++nt) {
    const unsigned short* bp = &Wt[(nt * 16 + l15) * 136 + g * 8];
    short8 bf0 = *(const short8*)(bp);
    short8 bf1 = *(const short8*)(bp + 32);
    short8 bf2 = *(const short8*)(bp + 64);
    short8 bf3 = *(const short8*)(bp + 96);
    f32x4 acc0 = {0.f, 0.f, 0.f, 0.f};
    f32x4 acc1 = {0.f, 0.f, 0.f, 0.f};
    acc0 = __builtin_amdgcn_mfma_f32_16x16x32_bf16(a[0][0], bf0, acc0, 0, 0, 0);
    acc0 = __builtin_amdgcn_mfma_f32_16x16x32_bf16(a[0][1], bf1, acc0, 0, 0, 0);
    acc0 = __builtin_amdgcn_mfma_f32_16x16x32_bf16(a[0][2], bf2, acc0, 0, 0, 0);
    acc0 = __builtin_amdgcn_mfma_f32_16x16x32_bf16(a[0][3], bf3, acc0, 0, 0, 0);
    acc1 = __builtin_amdgcn_mfma_f32_16x16x32_bf16(a[1][0], bf0, acc1, 0, 0, 0);
    acc1 = __builtin_amdgcn_mfma_f32_16x16x32_bf16(a[1][1], bf1, acc1, 0, 0, 0);
    acc1 = __builtin_amdgcn_mfma_f32_16x16x32_bf16(a[1][2], bf2, acc1, 0, 0, 0);
    acc1 = __builtin_amdgcn_mfma_f32_16x16x32_bf16(a[1][3], bf3, acc1, 0, 0, 0);
    int col = nt * 16 + l15;
    if (col < H3) {
#pragma unroll
      for (int r = 0; r < 4; ++r) {
        long rowA = row0 + g * 4 + r;          // C layout: row = (lane>>4)*4 + r
        xw[rowA * XW_STRIDE + col] = f2bf(acc0[r]);
        xw[(rowA + 16) * XW_STRIDE + col] = f2bf(acc1[r]);
      }
    }
  }
}

// ---------------- Phase 2: GRU scan + LeakyReLU + head + softmax -------------
// One block per batch row. Threads 0..149: inner[k] = b1[k] + sum_j h[j]*U[j][k].
// Threads 0..49 do gate math, keep h[j] in register, write h to LDS.
__global__ __launch_bounds__(192) void gru_head(const unsigned short* __restrict__ xw,
                                                const float* __restrict__ U,
                                                const float* __restrict__ bias,
                                                const float* __restrict__ W2,
                                                const float* __restrict__ b2,
                                                float* __restrict__ out) {
  __shared__ __align__(16) float h_lds[52];
  __shared__ float inner_lds[152];
  __shared__ float red[8];
  const int tid = threadIdx.x;
  const int b = blockIdx.x;
  const long base = (long)b * T_LEN * XW_STRIDE;

  float u[52];
#pragma unroll
  for (int j = 0; j < 52; ++j) u[j] = 0.f;
  float b1k = 0.f;
  if (tid < H3) {
#pragma unroll
    for (int j = 0; j < H; ++j) u[j] = U[j * H3 + tid];
    b1k = bias[H3 + tid];
  }
  float b0z = 0.f, b0r = 0.f, b0h = 0.f, hreg = 0.f;
  if (tid < H) {
    b0z = bias[tid];
    b0r = bias[H + tid];
    b0h = bias[2 * H + tid];
  }
  if (tid < 52) h_lds[tid] = 0.f;
  __syncthreads();

  unsigned short xz[4], xr[4], xh[4];
  if (tid < H) {
#pragma unroll
    for (int p = 0; p < 4; ++p) {
      long o = base + (long)p * XW_STRIDE;
      xz[p] = xw[o + tid];
      xr[p] = xw[o + H + tid];
      xh[p] = xw[o + 2 * H + tid];
    }
  }

  for (int t0 = 0; t0 < T_LEN; t0 += 4) {
#define STEP(P)                                                               \
    {                                                                         \
      float acc = b1k;                                                        \
      _Pragma("unroll")                                                       \
      for (int c = 0; c < 13; ++c) {                                          \
        f32x4 hv = *(const f32x4*)&h_lds[c * 4];                              \
        acc = fmaf(hv[0], u[c * 4 + 0], acc);                                 \
        acc = fmaf(hv[1], u[c * 4 + 1], acc);                                 \
        acc = fmaf(hv[2], u[c * 4 + 2], acc);                                 \
        acc = fmaf(hv[3], u[c * 4 + 3], acc);                                 \
      }                                                                       \
      if (tid >= H && tid < H3) inner_lds[tid] = acc;                         \
      __syncthreads();                                                        \
      if (tid < H) {                                                          \
        float iz = acc;                                                       \
        float ir = inner_lds[H + tid];                                        \
        float ih = inner_lds[2 * H + tid];                                    \
        float az = bf2f(xz[P]) + b0z + iz;                                    \
        float ar = bf2f(xr[P]) + b0r + ir;                                    \
        float zz = 1.f / (1.f + __expf(-az));                                 \
        float rr = 1.f / (1.f + __expf(-ar));                                 \
        float ah = bf2f(xh[P]) + b0h + rr * ih;                               \
        float e2 = __expf(2.f * fabsf(ah));                                   \
        float th = 1.f - 2.f / (e2 + 1.f);                                    \
        float hh = ah >= 0.f ? th : -th;                                      \
        hreg = zz * hreg + (1.f - zz) * hh;                                   \
        h_lds[tid] = hreg;                                                    \
        int tn = t0 + (P) + 4;                                                \
        if (tn < T_LEN) {                                                     \
          long o = base + (long)tn * XW_STRIDE;                               \
          xz[P] = xw[o + tid];                                                \
          xr[P] = xw[o + H + tid];                                            \
          xh[P] = xw[o + 2 * H + tid];                                        \
        }                                                                     \
      }                                                                       \
      __syncthreads();                                                        \
    }
    STEP(0) STEP(1) STEP(2) STEP(3)
#undef STEP
  }

  // LeakyReLU(0.3) + dense(50->8) + softmax
  if (tid < H) {
    float v = hreg >= 0.f ? hreg : 0.3f * hreg;
    inner_lds[tid] = v;
  }
  __syncthreads();
  if (tid < 8) {
    float acc = b2[tid];
#pragma unroll
    for (int j = 0; j < H; ++j) acc = fmaf(inner_lds[j], W2[j * 8 + tid], acc);
    red[tid] = acc;
  }
  __syncthreads();
  if (tid < 8) {
    float m = red[0];
#pragma unroll
    for (int i = 1; i < 8; ++i) m = fmaxf(m, red[i]);
    float s = 0.f;
#pragma unroll
    for (int i = 0; i < 8; ++i) s += __expf(red[i] - m);
    out[b * 8 + tid] = __expf(red[tid] - m) / s;
  }
}

extern "C" void kernel_launch(void* const* d_in, const int* in_sizes, int n_in,
                              void* d_out, int out_size, void* d_ws, size_t ws_size,
                              hipStream_t stream) {
  const float* x = (const float*)d_in[0];
  const float* W = (const float*)d_in[1];
  const float* U = (const float*)d_in[2];
  const float* bias = (const float*)d_in[3];
  const float* W2 = (const float*)d_in[4];
  const float* b2 = (const float*)d_in[5];
  float* out = (float*)d_out;
  unsigned short* xw = (unsigned short*)d_ws;  // [B*T][160] bf16, needs ~168 MB

  xw_gemm<<<4096, 256, 0, stream>>>(x, W, xw);
  gru_head<<<256, 192, 0, stream>>>(xw, U, bias, W2, b2, out);
}

// Round 2
// 1669.311 us; speedup vs baseline: 1.0623x; 1.0623x over previous
//
#include <hip/hip_runtime.h>

typedef __attribute__((ext_vector_type(4))) float f32x4;
typedef __attribute__((ext_vector_type(2))) float f32x2;
typedef __attribute__((ext_vector_type(8))) short short8;

#define T_LEN 2048
#define B_SZ 256
#define FEATN 128
#define H 50
#define H3 150
#define XW_STRIDE 160

__device__ __forceinline__ unsigned short f2bf(float f) {
  unsigned int u = __float_as_uint(f);
  u = (u + 0x7fffu + ((u >> 16) & 1u)) >> 16;
  return (unsigned short)u;
}
__device__ __forceinline__ float bf2f(unsigned short s) {
  return __uint_as_float(((unsigned int)s) << 16);
}
__device__ __forceinline__ float rcpf(float x) { return __builtin_amdgcn_rcpf(x); }

// ---------------- Phase 1: xw[m][k] = x[m][:] @ W[:][k]  (bf16 out, no bias) ----
__global__ __launch_bounds__(256) void xw_gemm(const float* __restrict__ x,
                                               const float* __restrict__ W,
                                               unsigned short* __restrict__ xw) {
  __shared__ unsigned short Wt[160 * 136];  // [n][k], row stride 136
  const int tid = threadIdx.x;
  for (int idx = tid; idx < FEATN * H3; idx += 256) {
    int f = idx / H3;
    int n = idx - f * H3;
    Wt[n * 136 + f] = f2bf(W[idx]);
  }
  for (int idx = tid; idx < 10 * FEATN; idx += 256) {  // zero-pad n = 150..159
    int n = H3 + (idx >> 7);
    int f = idx & 127;
    Wt[n * 136 + f] = 0;
  }
  __syncthreads();

  const int wid = tid >> 6;
  const int lane = tid & 63;
  const int l15 = lane & 15;
  const int g = lane >> 4;
  const long row0 = (long)blockIdx.x * 128 + wid * 32;

  short8 a[2][4];
#pragma unroll
  for (int sub = 0; sub < 2; ++sub) {
    const float* xp = x + (row0 + sub * 16 + l15) * FEATN + g * 8;
#pragma unroll
    for (int kk = 0; kk < 4; ++kk) {
      f32x4 p0 = *(const f32x4*)(xp + kk * 32);
      f32x4 p1 = *(const f32x4*)(xp + kk * 32 + 4);
      short8 v;
      v[0] = (short)f2bf(p0[0]); v[1] = (short)f2bf(p0[1]);
      v[2] = (short)f2bf(p0[2]); v[3] = (short)f2bf(p0[3]);
      v[4] = (short)f2bf(p1[0]); v[5] = (short)f2bf(p1[1]);
      v[6] = (short)f2bf(p1[2]); v[7] = (short)f2bf(p1[3]);
      a[sub][kk] = v;
    }
  }

  for (int nt = 0; nt < 10; ++nt) {
    const unsigned short* bp = &Wt[(nt * 16 + l15) * 136 + g * 8];
    short8 bf0 = *(const short8*)(bp);
    short8 bf1 = *(const short8*)(bp + 32);
    short8 bf2 = *(const short8*)(bp + 64);
    short8 bf3 = *(const short8*)(bp + 96);
    f32x4 acc0 = {0.f, 0.f, 0.f, 0.f};
    f32x4 acc1 = {0.f, 0.f, 0.f, 0.f};
    acc0 = __builtin_amdgcn_mfma_f32_16x16x32_bf16(a[0][0], bf0, acc0, 0, 0, 0);
    acc0 = __builtin_amdgcn_mfma_f32_16x16x32_bf16(a[0][1], bf1, acc0, 0, 0, 0);
    acc0 = __builtin_amdgcn_mfma_f32_16x16x32_bf16(a[0][2], bf2, acc0, 0, 0, 0);
    acc0 = __builtin_amdgcn_mfma_f32_16x16x32_bf16(a[0][3], bf3, acc0, 0, 0, 0);
    acc1 = __builtin_amdgcn_mfma_f32_16x16x32_bf16(a[1][0], bf0, acc1, 0, 0, 0);
    acc1 = __builtin_amdgcn_mfma_f32_16x16x32_bf16(a[1][1], bf1, acc1, 0, 0, 0);
    acc1 = __builtin_amdgcn_mfma_f32_16x16x32_bf16(a[1][2], bf2, acc1, 0, 0, 0);
    acc1 = __builtin_amdgcn_mfma_f32_16x16x32_bf16(a[1][3], bf3, acc1, 0, 0, 0);
    int col = nt * 16 + l15;
    if (col < H3) {
#pragma unroll
      for (int r = 0; r < 4; ++r) {
        long rowA = row0 + g * 4 + r;
        xw[rowA * XW_STRIDE + col] = f2bf(acc0[r]);
        xw[(rowA + 16) * XW_STRIDE + col] = f2bf(acc1[r]);
      }
    }
  }
}

// ---------------- Phase 2: one wave64 per batch row, no barriers --------------
// Lane l (l<50): owns h[l], gate columns (l, l+50, l+100). h broadcast via
// duplicated LDS pairs {h,h} -> 25 uniform ds_read_b128 feed 50 v_pk_fma_f32
// (z,r packed) + 50 scalar FMA (hh). lgkmcnt-only fence keeps vmcnt prefetch
// in flight (a __syncthreads would drain it).
__global__ __launch_bounds__(64, 1) void gru_head64(const unsigned short* __restrict__ xw,
                                                    const float* __restrict__ U,
                                                    const float* __restrict__ bias,
                                                    const float* __restrict__ W2,
                                                    const float* __restrict__ b2,
                                                    float* __restrict__ out) {
  __shared__ __align__(16) float h_lds[104];  // 52 duplicated pairs {h,h}
  __shared__ float red[8];
  const int l = threadIdx.x;
  const int b = blockIdx.x;
  const int lc = l < H ? l : H - 1;
  const bool act = l < H;
  const long base = (long)b * T_LEN * XW_STRIDE;

  // Preload U columns (lc, lc+50, lc+100) into registers.
  f32x2 uzr[H];
  float uh[H];
#pragma unroll
  for (int j = 0; j < H; ++j) {
    uzr[j][0] = U[j * H3 + lc];
    uzr[j][1] = U[j * H3 + H + lc];
    uh[j] = U[j * H3 + 2 * H + lc];
  }
  const f32x2 bzr = {bias[lc] + bias[H3 + lc], bias[H + lc] + bias[H3 + H + lc]};
  const float b0h = bias[2 * H + lc];
  const float b1h = bias[H3 + 2 * H + lc];

  // init h = 0 (duplicated pairs), incl. padding
  if (l < 52) *(f32x2*)&h_lds[2 * l] = (f32x2){0.f, 0.f};
  asm volatile("s_waitcnt lgkmcnt(0)" ::: "memory");

  float hreg = 0.f;

  // prefetch ring (depth 4)
  unsigned short pz[4], pr[4], ph[4];
#pragma unroll
  for (int p = 0; p < 4; ++p) {
    long o = base + (long)p * XW_STRIDE;
    pz[p] = xw[o + lc];
    pr[p] = xw[o + H + lc];
    ph[p] = xw[o + 2 * H + lc];
  }

  const f32x4* hp = (const f32x4*)h_lds;

  for (int t0 = 0; t0 < T_LEN; t0 += 4) {
#define STEP(P)                                                               \
    {                                                                         \
      f32x2 a0 = bzr, a1 = {0.f, 0.f};                                        \
      float c0 = b1h, c1 = 0.f;                                               \
      _Pragma("unroll")                                                       \
      for (int c = 0; c < 25; ++c) {                                          \
        f32x4 v = hp[c];                                                      \
        f32x2 h0 = __builtin_shufflevector(v, v, 0, 1);                       \
        f32x2 h1 = __builtin_shufflevector(v, v, 2, 3);                       \
        a0 = h0 * uzr[2 * c] + a0;                                            \
        a1 = h1 * uzr[2 * c + 1] + a1;                                        \
        c0 = fmaf(v[0], uh[2 * c], c0);                                       \
        c1 = fmaf(v[2], uh[2 * c + 1], c1);                                   \
      }                                                                       \
      float xzf = bf2f(pz[P]);                                                \
      float xrf = bf2f(pr[P]);                                                \
      float xhf = bf2f(ph[P]);                                                \
      int tn = t0 + (P) + 4;                                                  \
      if (tn < T_LEN) {                                                       \
        long o = base + (long)tn * XW_STRIDE;                                 \
        pz[P] = xw[o + lc];                                                   \
        pr[P] = xw[o + H + lc];                                               \
        ph[P] = xw[o + 2 * H + lc];                                           \
      }                                                                       \
      f32x2 azr = a0 + a1;                                                    \
      float az = azr[0] + xzf;                                                \
      float ar = azr[1] + xrf;                                                \
      float zz = rcpf(1.f + __expf(-az));                                     \
      float rr = rcpf(1.f + __expf(-ar));                                     \
      float ah = fmaf(rr, c0 + c1, xhf + b0h);                                \
      float th = fmaf(2.f, rcpf(1.f + __expf(-2.f * ah)), -1.f);              \
      hreg = fmaf(zz, hreg - th, th);                                         \
      if (act) *(f32x2*)&h_lds[2 * l] = (f32x2){hreg, hreg};                  \
      asm volatile("s_waitcnt lgkmcnt(0)" ::: "memory");                      \
    }
    STEP(0) STEP(1) STEP(2) STEP(3)
#undef STEP
  }

  // LeakyReLU + dense(50->8) + softmax (all within the single wave)
  if (act) {
    float v = hreg >= 0.f ? hreg : 0.3f * hreg;
    *(f32x2*)&h_lds[2 * l] = (f32x2){v, v};
  }
  asm volatile("s_waitcnt lgkmcnt(0)" ::: "memory");
  if (l < 8) {
    float acc = b2[l];
#pragma unroll
    for (int j = 0; j < H; ++j) acc = fmaf(h_lds[2 * j], W2[j * 8 + l], acc);
    red[l] = acc;
  }
  asm volatile("s_waitcnt lgkmcnt(0)" ::: "memory");
  if (l < 8) {
    float m = red[0];
#pragma unroll
    for (int i = 1; i < 8; ++i) m = fmaxf(m, red[i]);
    float s = 0.f;
#pragma unroll
    for (int i = 0; i < 8; ++i) s += __expf(red[i] - m);
    out[b * 8 + l] = __expf(red[l] - m) / s;
  }
}

extern "C" void kernel_launch(void* const* d_in, const int* in_sizes, int n_in,
                              void* d_out, int out_size, void* d_ws, size_t ws_size,
                              hipStream_t stream) {
  const float* x = (const float*)d_in[0];
  const float* W = (const float*)d_in[1];
  const float* U = (const float*)d_in[2];
  const float* bias = (const float*)d_in[3];
  const float* W2 = (const float*)d_in[4];
  const float* b2 = (const float*)d_in[5];
  float* out = (float*)d_out;
  unsigned short* xw = (unsigned short*)d_ws;  // [B*T][160] bf16

  xw_gemm<<<4096, 256, 0, stream>>>(x, W, xw);
  gru_head64<<<256, 64, 0, stream>>>(xw, U, bias, W2, b2, out);
}

// Round 3
// 618.923 us; speedup vs baseline: 2.8652x; 2.6971x over previous
//
#include <hip/hip_runtime.h>

typedef __attribute__((ext_vector_type(4))) float f32x4;
typedef _Float16 f16;
typedef __attribute__((ext_vector_type(2))) _Float16 f16x2;
typedef __attribute__((ext_vector_type(8))) _Float16 f16x8;

#define T_LEN 2048
#define B_SZ 256
#define FEATN 128
#define H 50
#define H3 150
#define XW_STRIDE 160

__device__ __forceinline__ float rcpf(float x) { return __builtin_amdgcn_rcpf(x); }

__device__ __forceinline__ float dot2f(f16x2 a, f16x2 b, float c) {
#if __has_builtin(__builtin_amdgcn_fdot2)
  return __builtin_amdgcn_fdot2(a, b, c, false);
#else
  return fmaf((float)a[1], (float)b[1], fmaf((float)a[0], (float)b[0], c));
#endif
}

// ---------------- Phase 1: xw[m][k] = x[m][:] @ W[:][k]  (f16 out, no bias) ----
__global__ __launch_bounds__(256) void xw_gemm(const float* __restrict__ x,
                                               const float* __restrict__ W,
                                               f16* __restrict__ xw) {
  __shared__ f16 Wt[160 * 136];  // [n][k], row stride 136 halves (16B-aligned rows)
  const int tid = threadIdx.x;
  for (int idx = tid; idx < FEATN * H3; idx += 256) {
    int f = idx / H3;
    int n = idx - f * H3;
    Wt[n * 136 + f] = (f16)W[idx];
  }
  for (int idx = tid; idx < 10 * FEATN; idx += 256) {  // zero-pad n = 150..159
    int n = H3 + (idx >> 7);
    int f = idx & 127;
    Wt[n * 136 + f] = (f16)0.f;
  }
  __syncthreads();

  const int wid = tid >> 6;
  const int lane = tid & 63;
  const int l15 = lane & 15;
  const int g = lane >> 4;
  const long row0 = (long)blockIdx.x * 128 + wid * 32;

  // A fragments: lane holds row=l15, k = kk*32 + g*8 + j
  f16x8 a[2][4];
#pragma unroll
  for (int sub = 0; sub < 2; ++sub) {
    const float* xp = x + (row0 + sub * 16 + l15) * FEATN + g * 8;
#pragma unroll
    for (int kk = 0; kk < 4; ++kk) {
      f32x4 p0 = *(const f32x4*)(xp + kk * 32);
      f32x4 p1 = *(const f32x4*)(xp + kk * 32 + 4);
      f16x8 v;
      v[0] = (f16)p0[0]; v[1] = (f16)p0[1]; v[2] = (f16)p0[2]; v[3] = (f16)p0[3];
      v[4] = (f16)p1[0]; v[5] = (f16)p1[1]; v[6] = (f16)p1[2]; v[7] = (f16)p1[3];
      a[sub][kk] = v;
    }
  }

  for (int nt = 0; nt < 10; ++nt) {
    const f16* bp = &Wt[(nt * 16 + l15) * 136 + g * 8];
    f16x8 bf0 = *(const f16x8*)(bp);
    f16x8 bf1 = *(const f16x8*)(bp + 32);
    f16x8 bf2 = *(const f16x8*)(bp + 64);
    f16x8 bf3 = *(const f16x8*)(bp + 96);
    f32x4 acc0 = {0.f, 0.f, 0.f, 0.f};
    f32x4 acc1 = {0.f, 0.f, 0.f, 0.f};
    acc0 = __builtin_amdgcn_mfma_f32_16x16x32_f16(a[0][0], bf0, acc0, 0, 0, 0);
    acc0 = __builtin_amdgcn_mfma_f32_16x16x32_f16(a[0][1], bf1, acc0, 0, 0, 0);
    acc0 = __builtin_amdgcn_mfma_f32_16x16x32_f16(a[0][2], bf2, acc0, 0, 0, 0);
    acc0 = __builtin_amdgcn_mfma_f32_16x16x32_f16(a[0][3], bf3, acc0, 0, 0, 0);
    acc1 = __builtin_amdgcn_mfma_f32_16x16x32_f16(a[1][0], bf0, acc1, 0, 0, 0);
    acc1 = __builtin_amdgcn_mfma_f32_16x16x32_f16(a[1][1], bf1, acc1, 0, 0, 0);
    acc1 = __builtin_amdgcn_mfma_f32_16x16x32_f16(a[1][2], bf2, acc1, 0, 0, 0);
    acc1 = __builtin_amdgcn_mfma_f32_16x16x32_f16(a[1][3], bf3, acc1, 0, 0, 0);
    int col = nt * 16 + l15;
    if (col < H3) {
#pragma unroll
      for (int r = 0; r < 4; ++r) {
        long rowA = row0 + g * 4 + r;  // C layout: row = (lane>>4)*4 + r, col = lane&15
        xw[rowA * XW_STRIDE + col] = (f16)acc0[r];
        xw[(rowA + 16) * XW_STRIDE + col] = (f16)acc1[r];
      }
    }
  }
}

// ---------------- Phase 2: one wave64 per batch row, no fences ---------------
// Lane l<50 owns h[l] and gate columns (l, l+50, l+100). h broadcast through
// LDS as f16 (ds ops from one wave execute in order -> no waitcnt needed for
// the write->read RAW; compiler inserts precise counted waits for register
// hazards, so the global xw prefetch ring stays in flight).
__global__ __launch_bounds__(64, 1) void gru_head64(const f16* __restrict__ xw,
                                                    const float* __restrict__ U,
                                                    const float* __restrict__ bias,
                                                    const float* __restrict__ W2,
                                                    const float* __restrict__ b2,
                                                    float* __restrict__ out) {
  __shared__ __align__(4) f16 h_lds16[64];
  __shared__ float fin[52];
  __shared__ float red[8];
  const int l = threadIdx.x;
  const int b = blockIdx.x;
  const int lc = l < H ? l : H - 1;
  const bool act = l < H;
  const long base = (long)b * T_LEN * XW_STRIDE;

  // U columns (z,r,h) for this lane, packed as f16 pairs over j: 75 VGPRs.
  f16x2 uz2[25], ur2[25], uh2[25];
#pragma unroll
  for (int c = 0; c < 25; ++c) {
    uz2[c][0] = (f16)U[(2 * c) * H3 + lc];
    uz2[c][1] = (f16)U[(2 * c + 1) * H3 + lc];
    ur2[c][0] = (f16)U[(2 * c) * H3 + H + lc];
    ur2[c][1] = (f16)U[(2 * c + 1) * H3 + H + lc];
    uh2[c][0] = (f16)U[(2 * c) * H3 + 2 * H + lc];
    uh2[c][1] = (f16)U[(2 * c + 1) * H3 + 2 * H + lc];
  }
  const float bz = bias[lc] + bias[H3 + lc];
  const float br = bias[H + lc] + bias[H3 + H + lc];
  const float b0h = bias[2 * H + lc];
  const float b1h = bias[H3 + 2 * H + lc];

  h_lds16[l] = (f16)0.f;  // all 64 lanes; only [0..49] ever read

  float hreg = 0.f;

  // prefetch ring, depth 8 (branch-free wrapped addresses)
  f16 pz[8], pr[8], ph[8];
#pragma unroll
  for (int p = 0; p < 8; ++p) {
    long o = base + (long)p * XW_STRIDE;
    pz[p] = xw[o + lc];
    pr[p] = xw[o + H + lc];
    ph[p] = xw[o + 2 * H + lc];
  }

  const f16x2* hp2 = (const f16x2*)h_lds16;

  for (int t0 = 0; t0 < T_LEN; t0 += 8) {
#define STEP(P)                                                               \
    {                                                                         \
      float sz = bz, sr = br, sh = b1h;                                       \
      _Pragma("unroll")                                                       \
      for (int c = 0; c < 25; ++c) {                                          \
        f16x2 hv = hp2[c];                                                    \
        sz = dot2f(hv, uz2[c], sz);                                           \
        sr = dot2f(hv, ur2[c], sr);                                           \
        sh = dot2f(hv, uh2[c], sh);                                           \
      }                                                                       \
      float xzf = (float)pz[P];                                               \
      float xrf = (float)pr[P];                                               \
      float xhf = (float)ph[P];                                               \
      {                                                                       \
        int tn = (t0 + (P) + 8) & (T_LEN - 1);                                \
        long o = base + (long)tn * XW_STRIDE;                                 \
        pz[P] = xw[o + lc];                                                   \
        pr[P] = xw[o + H + lc];                                               \
        ph[P] = xw[o + 2 * H + lc];                                           \
      }                                                                       \
      float az = sz + xzf;                                                    \
      float ar = sr + xrf;                                                    \
      float zz = rcpf(1.f + __expf(-az));                                     \
      float rr = rcpf(1.f + __expf(-ar));                                     \
      float ah = fmaf(rr, sh, xhf + b0h);                                     \
      float th = fmaf(2.f, rcpf(1.f + __expf(-2.f * ah)), -1.f);              \
      hreg = fmaf(zz, hreg - th, th);                                         \
      h_lds16[l] = (f16)hreg;                                                 \
    }
    STEP(0) STEP(1) STEP(2) STEP(3) STEP(4) STEP(5) STEP(6) STEP(7)
#undef STEP
  }

  // LeakyReLU(0.3) + dense(50->8) + softmax, single wave, in-order LDS
  if (act) {
    fin[l] = hreg >= 0.f ? hreg : 0.3f * hreg;
  }
  if (l < 8) {
    float acc = b2[l];
#pragma unroll
    for (int j = 0; j < H; ++j) acc = fmaf(fin[j], W2[j * 8 + l], acc);
    red[l] = acc;
  }
  if (l < 8) {
    float m = red[0];
#pragma unroll
    for (int i = 1; i < 8; ++i) m = fmaxf(m, red[i]);
    float s = 0.f;
#pragma unroll
    for (int i = 0; i < 8; ++i) s += __expf(red[i] - m);
    out[b * 8 + l] = __expf(red[l] - m) / s;
  }
}

extern "C" void kernel_launch(void* const* d_in, const int* in_sizes, int n_in,
                              void* d_out, int out_size, void* d_ws, size_t ws_size,
                              hipStream_t stream) {
  const float* x = (const float*)d_in[0];
  const float* W = (const float*)d_in[1];
  const float* U = (const float*)d_in[2];
  const float* bias = (const float*)d_in[3];
  const float* W2 = (const float*)d_in[4];
  const float* b2 = (const float*)d_in[5];
  float* out = (float*)d_out;
  f16* xw = (f16*)d_ws;  // [B*T][160] f16, ~168 MB

  xw_gemm<<<4096, 256, 0, stream>>>(x, W, xw);
  gru_head64<<<256, 64, 0, stream>>>(xw, U, bias, W2, b2, out);
}